// Round 7
// baseline (451.093 us; speedup 1.0000x reference)
//
#include <hip/hip_runtime.h>
#include <math.h>

// PhaseNN on MI355X.  ROUND 18: i8 K=64 MFMA conversion (fp8 K=32 -> i8 K=64).
// R17 post-mortem (374 us): per-CU eval ~14000cy = stream 6100 + MFMA 5000 +
// VALU 4400, barely overlapped; VALU-halving returns collapsed (R17 bought
// half its prediction).  Attack the MFMA term: mfma_i32_16x16x64_i8 runs at
// 2x the non-scaled fp8 K=32 rate (3944 TOPS ubench) -> GEMM1/GEMM2 MFMA count
// halves (16+16 per wave vs 32+32) at identical table bytes (8b/elem).
//  - Tables/feats/w quantized i8 (x127); int32 accumulation exact.
//  - Accuracy expected to IMPROVE: i8 cos/sin err 1/254 uniform vs e4m3 1/32
//    near |x|~1; w err 1/127-of-unit vs fp8 ~3% near max.  absmax WILL change.
//  - Fragment layout: family pattern scaled x2 (lane q covers k = q*16+i,
//    LSB-first); D layout unchanged; all swizzles drop to linear (16B reads
//    are 2-way/broadcast = free).
// Structure otherwise identical to R17: 128 blocks x 2 rows, 16 waves, 3
// barriers/eval, T2 ct<36 in LDS (144K) / ct>=36 global, T1 global.
// Tripwire: WRITE_SIZE > 5 MB = spill -> revert.

typedef __attribute__((ext_vector_type(4))) float f32x4;
typedef __attribute__((ext_vector_type(4))) int   i32x4;
typedef __attribute__((ext_vector_type(8))) short bf16x8;
typedef __attribute__((ext_vector_type(2))) unsigned short u16x2;

struct TCons { float s[64]; float c[64]; };

__device__ __forceinline__ unsigned short f2bf(float f) {
  unsigned u = __builtin_bit_cast(unsigned, f);
  return (unsigned short)((u + 0x7FFFu + ((u >> 16) & 1u)) >> 16);
}
// pack 4 floats (|v|<=1) -> 4 i8 bytes scaled x127, LSB first
__device__ __forceinline__ int pk4i8(const float* v) {
  int a = __float2int_rn(v[0]*127.0f) & 255;
  int b = __float2int_rn(v[1]*127.0f) & 255;
  int c = __float2int_rn(v[2]*127.0f) & 255;
  int d = __float2int_rn(v[3]*127.0f);
  return a | (b << 8) | (c << 16) | (d << 24);
}

#define A1_OFF    0        // feats i8: 2 rows x [cos 1024 | sin 1024]; epilogue bf16 2x4096
#define MBUF_OFF  8192     // m partials i32: 2 kh x 2 rows x 132 (kh stride 1056)
#define W_OFF     10304    // w i8 (x127): 2 rows x 128 B = 256
#define ZP_OFF    10560    // 16 B zero page (bf16 epilogue pad cols)
#define XST_OFF   10576    // 2 rows x 104 chunks x 16 B bf16 (encoder prologue only)
#define T2L_OFF   13904    // T2 ct 0..35: 72 frag-pairs x 2048 B = 147456
#define RED_OFF   13904    // epilogue overlay (T2L dead by then): 16 KiB
#define LDS_BYTES 161360   // ~157.6 KiB of 160 KiB

__global__
__attribute__((amdgpu_flat_work_group_size(1024, 1024), amdgpu_waves_per_eu(4, 4)))
void phasenn_kernel(
    const float* __restrict__ x, const float* __restrict__ W_enc,
    const float* __restrict__ b_enc, const float* __restrict__ xi,
    const float* __restrict__ W_out, const float* __restrict__ b_out,
    float* __restrict__ dout, char* __restrict__ wsb, TCons tc)
{
  __shared__ __align__(16) char smem[LDS_BYTES];

  const int tid  = threadIdx.x;
  const int bk   = blockIdx.x;        // rows bk*2, bk*2+1
  const int w    = tid >> 6;          // 16 waves
  const int lane = tid & 63;
  const int q    = lane >> 4;
  const int b16  = lane & 15;         // MFMA col slot (batch row duplicated x8)
  const int row2 = b16 & 1;           // batch row within block
  const int j4   = b16 >> 2;          // lane's n-subtile j (0..3)
  const int rp   = (b16 >> 1) & 1;    // lane's r-pair (r = rp*2 + {0,1})

  char* T1g = wsb;                    // 256 KiB: (pt 8, F 16) frag-pairs x 64 lanes x 32 B
  char* T2g = wsb + (256 << 10);      // ct>=36: (ct*2+P2) frag-pairs x 64 lanes x 32 B

  // ---- LDS init: zero page only
  if (tid < 4) *(unsigned*)(smem + ZP_OFF + tid*4) = 0;

  // ---- xstage: x rows -> bf16 B-frag chunks (chunk ^ row), d>=784 zero (encoder)
  {
    const int row = tid >> 7, dg = tid & 127;
    if (row < 2 && dg < 100) {
      bf16x8 fr = {0,0,0,0,0,0,0,0};
      if (dg < 98) {
        f32x4 v0 = *(const f32x4*)(x + (bk*2 + row)*784 + dg*8);
        f32x4 v1 = *(const f32x4*)(x + (bk*2 + row)*784 + dg*8 + 4);
        #pragma unroll
        for (int i = 0; i < 8; ++i) fr[i] = (short)f2bf(i < 4 ? v0[i] : v1[i-4]);
      }
      *(bf16x8*)(smem + XST_OFF + row*1664 + (((dg ^ row) & 127) << 4)) = fr;
    }
  }

  // ---- table gen: i8 frag-pairs [cos16|sin16], 32 B/lane.
  if (w < 8) {  // T1: wave = ptile. lane: p = w*16+b16, n = F*64 + q*16 + i
    const int p = w*16 + b16;
    for (int F = 0; F < 16; ++F) {
      const int n0 = F*64 + q*16;
      f32x4 v0 = *(const f32x4*)(xi + p*1024 + n0);
      f32x4 v1 = *(const f32x4*)(xi + p*1024 + n0 + 4);
      f32x4 v2 = *(const f32x4*)(xi + p*1024 + n0 + 8);
      f32x4 v3 = *(const f32x4*)(xi + p*1024 + n0 + 12);
      float cv[16], sv[16];
      #pragma unroll
      for (int i = 0; i < 16; ++i) {
        float xv = (i < 4) ? v0[i] : (i < 8) ? v1[i-4] : (i < 12) ? v2[i-8] : v3[i-12];
        sv[i] = __sinf(xv); cv[i] = __cosf(xv);
      }
      i32x4 C = { pk4i8(cv), pk4i8(cv+4), pk4i8(cv+8), pk4i8(cv+12) };
      i32x4 S = { pk4i8(sv), pk4i8(sv+4), pk4i8(sv+8), pk4i8(sv+12) };
      char* dst = T1g + (size_t)(w*16 + F)*2048 + lane*32;
      *(i32x4*)(dst) = C; *(i32x4*)(dst + 16) = S;
    }
  } else {      // T2: lane: n = ct*16+b16, p = P2*64 + q*16 + i
    const int w2 = w - 8;
    for (int f = 0; f < 16; ++f) {
      const int ct = w2*8 + (f >> 1), P2 = f & 1;
      const int n = ct*16 + b16;
      float cv[16], sv[16];
      #pragma unroll
      for (int i = 0; i < 16; ++i) {
        float xv = xi[(P2*64 + q*16 + i)*1024 + n];
        sv[i] = __sinf(xv); cv[i] = __cosf(xv);
      }
      i32x4 C = { pk4i8(cv), pk4i8(cv+4), pk4i8(cv+8), pk4i8(cv+12) };
      i32x4 S = { pk4i8(sv), pk4i8(sv+4), pk4i8(sv+8), pk4i8(sv+12) };
      char* dst = (ct < 36)
          ? (smem + T2L_OFF + (size_t)(ct*2 + P2)*2048 + lane*32)
          : (T2g + (size_t)(ct*2 + P2)*2048 + lane*32);
      *(i32x4*)(dst) = C; *(i32x4*)(dst + 16) = S;
    }
  }
  __syncthreads();

  // ---- encoder (bf16 MFMA): unchanged from R17.  Lane keeps 2 phases:
  // n = (w*4+j4)*16 + q*4 + rp*2 + {0,1}, batch row row2.
  float p0[2], ka[2], pwv[2];
  {
    f32x4 pac[4] = {{0,0,0,0},{0,0,0,0},{0,0,0,0},{0,0,0,0}};
    for (int kt = 0; kt < 25; ++kt) {
      const char* baddr =
          smem + XST_OFF + row2*1664 + ((((kt*4 + q) ^ row2) & 127) << 4);
      bf16x8 bfr = *(const bf16x8*)baddr;
      const int d = kt*32 + q*8;
      #pragma unroll
      for (int j = 0; j < 4; ++j) {
        bf16x8 afr = {0,0,0,0,0,0,0,0};
        if (d < 784) {
          const int n = (w*4 + j)*16 + b16;
          f32x4 v0 = *(const f32x4*)(W_enc + n*784 + d);
          f32x4 v1 = *(const f32x4*)(W_enc + n*784 + d + 4);
          #pragma unroll
          for (int i = 0; i < 8; ++i) afr[i] = (short)f2bf(i < 4 ? v0[i] : v1[i-4]);
        }
        pac[j] = __builtin_amdgcn_mfma_f32_16x16x32_bf16(afr, bfr, pac[j], 0, 0, 0);
      }
    }
    f32x4 pc = (j4==0) ? pac[0] : (j4==1) ? pac[1] : (j4==2) ? pac[2] : pac[3];
    float vA = rp ? pc[2] : pc[0];
    float vB = rp ? pc[3] : pc[1];
    const int n0 = (w*4 + j4)*16 + q*4 + rp*2;
    float ph0 = 6.283185307179586f / (1.0f + __expf(-(vA + b_enc[n0])));
    float ph1 = 6.283185307179586f / (1.0f + __expf(-(vB + b_enc[n0 + 1])));
    p0[0] = ph0; pwv[0] = ph0; ka[0] = 0.0f;
    p0[1] = ph1; pwv[1] = ph1; ka[1] = 0.0f;
  }

  const float dtf = 0.03125f, half = 0.015625f;
  const float sixth = (float)(0.03125/6.0);
  const float mscale = (float)(2.0 / (1024.0 * 16129.0));   // BETA/N / 127^2
  const float kscale = (float)(1.0 / 16129.0);              // 1/127^2

  for (int e = 0; e < 64; ++e) {
    float csv[2], snv[2];
    // ---- Phase A: all 64 lanes, 2 phases each; i8 feats, linear layout
    {
      #pragma unroll
      for (int r = 0; r < 2; ++r) {
        snv[r] = __sinf(pwv[r]);
        csv[r] = __cosf(pwv[r]);
      }
      int c0 = __float2int_rn(csv[0]*127.0f) & 255;
      int c1 = __float2int_rn(csv[1]*127.0f) & 255;
      int s0 = __float2int_rn(snv[0]*127.0f) & 255;
      int s1 = __float2int_rn(snv[1]*127.0f) & 255;
      const int n0 = (w*4 + j4)*16 + q*4 + rp*2;
      char* base = smem + A1_OFF + row2*2048 + n0;
      *(unsigned short*)(base)        = (unsigned short)(c0 | (c1 << 8));
      *(unsigned short*)(base + 1024) = (unsigned short)(s0 | (s1 << 8));
    }
    __syncthreads();

    // ---- GEMM1 i8 K=64: m[p][row]; wave = (pt=w&7, kh=w>>3); 16 MFMA/wave
    {
      const int pt = w & 7, kh = w >> 3;
      i32x4 accC = {0,0,0,0}, accS = {0,0,0,0};
      const char* t1b = T1g + (size_t)(pt*16 + kh*8)*2048 + lane*32;
      const char* a1b = smem + A1_OFF + row2*2048;
      #pragma unroll
      for (int i2 = 0; i2 < 8; ++i2) {
        const int F = kh*8 + i2;
        i32x4 ca = *(const i32x4*)(t1b + (size_t)i2*2048);
        i32x4 sa = *(const i32x4*)(t1b + (size_t)i2*2048 + 16);
        i32x4 bc = *(const i32x4*)(a1b + F*64 + q*16);
        i32x4 bs = *(const i32x4*)(a1b + 1024 + F*64 + q*16);
        accC = __builtin_amdgcn_mfma_i32_16x16x64_i8(ca, bc, accC, 0, 0, 0);
        accS = __builtin_amdgcn_mfma_i32_16x16x64_i8(sa, bs, accS, 0, 0, 0);
      }
      if (b16 < 2) {
        i32x4 acc = accC + accS;
        *(i32x4*)(smem + MBUF_OFF + kh*1056 + b16*528 + ((pt*16 + q*4) << 2)) = acc;
      }
    }
    __syncthreads();

    // ---- softmax (waves 0..1, wave = row): exact i32 m; w i8 (x127), linear
    if (w < 2) {
      const char* mb = smem + MBUF_OFF + w*528 + lane*8;
      int a0 = *(const int*)(mb),        a1 = *(const int*)(mb + 4);
      int b0 = *(const int*)(mb + 1056), b1 = *(const int*)(mb + 1056 + 4);
      float e0 = __expf((float)(a0 + b0) * mscale);
      float e1 = __expf((float)(a1 + b1) * mscale);
      float s = e0 + e1;
      #pragma unroll
      for (int off = 1; off < 64; off <<= 1) s += __shfl_xor(s, off, 64);
      const float inv = 127.0f / s;
      int w0 = __float2int_rn(e0 * inv);
      int w1 = __float2int_rn(e1 * inv);
      *(unsigned short*)(smem + W_OFF + w*128 + lane*2) =
          (unsigned short)((w0 & 255) | (w1 << 8));
    }
    __syncthreads();

    // ---- GEMM2 i8 K=64 + RK4: waves 0..8 read T2 from LDS, 9..15 global.
    // 4 ct x 2 P2 pairs = 16 MFMA/wave; lane selects (j4, rp); cached trig.
    {
      const float swt = tc.s[e], cwt = tc.c[e];
      const int st = e & 3;
      i32x4 wf0 = *(const i32x4*)(smem + W_OFF + row2*128 + q*16);
      i32x4 wf1 = *(const i32x4*)(smem + W_OFF + row2*128 + 64 + q*16);
      i32x4 aC[4] = {{0,0,0,0},{0,0,0,0},{0,0,0,0},{0,0,0,0}};
      i32x4 aS[4] = {{0,0,0,0},{0,0,0,0},{0,0,0,0},{0,0,0,0}};
      if (w < 9) {
        const char* t2b = smem + T2L_OFF + (size_t)(w*8)*2048 + lane*32;
        #pragma unroll
        for (int c = 0; c < 4; ++c)
          #pragma unroll
          for (int P2 = 0; P2 < 2; ++P2) {
            i32x4 ct_ = *(const i32x4*)(t2b + (size_t)(c*2 + P2)*2048);
            i32x4 st_ = *(const i32x4*)(t2b + (size_t)(c*2 + P2)*2048 + 16);
            i32x4 wf = P2 ? wf1 : wf0;
            aC[c] = __builtin_amdgcn_mfma_i32_16x16x64_i8(ct_, wf, aC[c], 0, 0, 0);
            aS[c] = __builtin_amdgcn_mfma_i32_16x16x64_i8(st_, wf, aS[c], 0, 0, 0);
          }
      } else {
        const char* t2b = T2g + (size_t)(w*8)*2048 + lane*32;
        #pragma unroll
        for (int c = 0; c < 4; ++c)
          #pragma unroll
          for (int P2 = 0; P2 < 2; ++P2) {
            i32x4 ct_ = *(const i32x4*)(t2b + (size_t)(c*2 + P2)*2048);
            i32x4 st_ = *(const i32x4*)(t2b + (size_t)(c*2 + P2)*2048 + 16);
            i32x4 wf = P2 ? wf1 : wf0;
            aC[c] = __builtin_amdgcn_mfma_i32_16x16x64_i8(ct_, wf, aC[c], 0, 0, 0);
            aS[c] = __builtin_amdgcn_mfma_i32_16x16x64_i8(st_, wf, aS[c], 0, 0, 0);
          }
      }
      i32x4 c4 = (j4==0) ? aC[0] : (j4==1) ? aC[1] : (j4==2) ? aC[2] : aC[3];
      i32x4 s4 = (j4==0) ? aS[0] : (j4==1) ? aS[1] : (j4==2) ? aS[2] : aS[3];
      float vC[2], vS[2];
      vC[0] = (float)(rp ? c4[2] : c4[0]);  vC[1] = (float)(rp ? c4[3] : c4[1]);
      vS[0] = (float)(rp ? s4[2] : s4[0]);  vS[1] = (float)(rp ? s4[3] : s4[1]);
      #pragma unroll
      for (int r = 0; r < 2; ++r) {
        float s_ = snv[r];
        float c_ = csv[r];
        float kv = (s_*vC[r] - c_*vS[r]) * kscale
                 + 0.08f*(swt*c_ - cwt*s_);            // A*sin(wt - phi)
        if (st == 0)      { ka[r]  = kv;           pwv[r] = p0[r] + kv*half; }
        else if (st == 1) { ka[r] += 2.0f*kv;      pwv[r] = p0[r] + kv*half; }
        else if (st == 2) { ka[r] += 2.0f*kv;      pwv[r] = p0[r] + kv*dtf;  }
        else { ka[r] += kv; p0[r] += ka[r]*sixth; pwv[r] = p0[r]; }
      }
    }
  }

  // ---- epilogue (bf16 MFMA): out = [cos phiT, sin phiT] @ W_out^T + b_out
  __syncthreads();
  {  // pack feats bf16 into A1 region (rows 0..1, 4-KB stride); all lanes, 2 each
    u16x2 cp, sp;
    #pragma unroll
    for (int r = 0; r < 2; ++r) {
      float ph = p0[r];
      cp[r] = f2bf(__cosf(ph)); sp[r] = f2bf(__sinf(ph));
    }
    const int cj = (w*4 + j4)*2 + (q >> 1);
    char* base = smem + A1_OFF + row2*4096 + ((q & 1) << 3) + rp*4;
    *(u16x2*)(base + ((cj ^ row2) << 4))        = cp;
    *(u16x2*)(base + ((cj ^ row2) << 4) + 2048) = sp;
  }
  __syncthreads();
  {  // D[cl][row] partial over this wave's 4 ktiles; A = W_out rows (cl<10, pad 0)
    f32x4 acc = {0.f, 0.f, 0.f, 0.f};
    #pragma unroll
    for (int i2 = 0; i2 < 4; ++i2) {
      const int kt = w*4 + i2;
      const int k = kt*32 + q*8;
      bf16x8 afr = {0,0,0,0,0,0,0,0};
      if (b16 < 10) {
        f32x4 v0 = *(const f32x4*)(W_out + b16*2048 + k);
        f32x4 v1 = *(const f32x4*)(W_out + b16*2048 + k + 4);
        #pragma unroll
        for (int i = 0; i < 8; ++i) afr[i] = (short)f2bf(i < 4 ? v0[i] : v1[i-4]);
      }
      const char* baddr = (b16 < 2)
          ? (smem + A1_OFF + b16*4096 + ((((kt*4 + q) ^ b16) & 255) << 4))
          : (smem + ZP_OFF);
      bf16x8 bfr = *(const bf16x8*)baddr;
      acc = __builtin_amdgcn_mfma_f32_16x16x32_bf16(afr, bfr, acc, 0, 0, 0);
    }
    *(f32x4*)(smem + RED_OFF + ((w*64 + lane) << 4)) = acc;
  }
  __syncthreads();
  if (tid < 64) {   // reduce 16 wave-partials; lane: row = tid&15, cl = (tid>>4)*4+r
    f32x4 s = {0.f, 0.f, 0.f, 0.f};
    #pragma unroll
    for (int w2 = 0; w2 < 16; ++w2)
      s += *(const f32x4*)(smem + RED_OFF + ((w2*64 + tid) << 4));
    const int b = tid & 15, q2 = tid >> 4;
    if (b < 2) {
      #pragma unroll
      for (int r = 0; r < 4; ++r) {
        const int cl = q2*4 + r;
        if (cl < 10)
          dout[(bk*2 + b)*10 + cl] = s[r] + b_out[cl];
      }
    }
  }
}

extern "C" void kernel_launch(void* const* d_in, const int* in_sizes, int n_in,
                              void* d_out, int out_size, void* d_ws, size_t ws_size,
                              hipStream_t stream) {
  (void)in_sizes; (void)n_in; (void)ws_size; (void)out_size;
  const float* x     = (const float*)d_in[0];
  const float* W_enc = (const float*)d_in[1];
  const float* b_enc = (const float*)d_in[2];
  const float* xi    = (const float*)d_in[3];
  const float* W_out = (const float*)d_in[4];
  const float* b_out = (const float*)d_in[5];
  float* out = (float*)d_out;
  char* wsb = (char*)d_ws;   // 512 KiB i8 tables; T1 + T2(ct>=36) rewritten per launch

  TCons tc;
  const double OME = 2.0 * 3.14159265358979323846 * 200.0;
  const double dtd = 0.03125;
  const double co[4] = {0.0, 0.5, 0.5, 1.0};
  for (int e = 0; e < 64; ++e) {
    double t = ((double)(e >> 2) + co[e & 3]) * dtd;
    tc.s[e] = (float)sin(OME * t);
    tc.c[e] = (float)cos(OME * t);
  }

  phasenn_kernel<<<dim3(128), dim3(1024), 0, stream>>>(
      x, W_enc, b_enc, xi, W_out, b_out, out, wsb, tc);
}

// Round 8
// 410.323 us; speedup vs baseline: 1.0994x; 1.0994x over previous
//
#include <hip/hip_runtime.h>
#include <math.h>

// PhaseNN on MI355X.  ROUND 19: R18 (i8 K=64) + bank-conflict fix.
// R18 post-mortem: 374->418 us regression == SQ_LDS_BANK_CONFLICT 4K->13.78M
// (13.78M cyc / 128 CU / 2.4GHz ~= 45 us == the regression).  Cause: 32 B/lane
// frag-pair layout ([cos16|sin16] interleaved) -> stride-32 ds_read/write_b128,
// ~8-way conflicts.  i8 itself was perf-neutral (MfmaUtil 15->7, halved MFMA
// absorbed by overlap), absmax 0.0156 passed.
// R19 fix (single variable): frag-pair = two 1024-B PLANES: cos @ lane*16,
// sin @ +1024.  All LDS/global accesses stride-16 contiguous (R17's proven
// pattern); values and MFMA order bit-identical to R18 -> absmax must stay
// EXACTLY 0.015625.
// Read of result: ~R17-parity => MFMA off critical path -> next: stream overlap
// (T2g reg prefetch; VGPR=56 leaves headroom).  350-365 => i8 halving exposed.
// Structure: 128 blocks x 2 rows, 16 waves, 3 barriers/eval, T2 ct<36 LDS
// (144K) / ct>=36 global, T1 global.  Tripwire: WRITE_SIZE > 5 MB = spill.

typedef __attribute__((ext_vector_type(4))) float f32x4;
typedef __attribute__((ext_vector_type(4))) int   i32x4;
typedef __attribute__((ext_vector_type(8))) short bf16x8;
typedef __attribute__((ext_vector_type(2))) unsigned short u16x2;

struct TCons { float s[64]; float c[64]; };

__device__ __forceinline__ unsigned short f2bf(float f) {
  unsigned u = __builtin_bit_cast(unsigned, f);
  return (unsigned short)((u + 0x7FFFu + ((u >> 16) & 1u)) >> 16);
}
// pack 4 floats (|v|<=1) -> 4 i8 bytes scaled x127, LSB first
__device__ __forceinline__ int pk4i8(const float* v) {
  int a = __float2int_rn(v[0]*127.0f) & 255;
  int b = __float2int_rn(v[1]*127.0f) & 255;
  int c = __float2int_rn(v[2]*127.0f) & 255;
  int d = __float2int_rn(v[3]*127.0f);
  return a | (b << 8) | (c << 16) | (d << 24);
}

#define A1_OFF    0        // feats i8: 2 rows x [cos 1024 | sin 1024]; epilogue bf16 2x4096
#define MBUF_OFF  8192     // m partials i32: 2 kh x 2 rows x 132 (kh stride 1056)
#define W_OFF     10304    // w i8 (x127): 2 rows x 128 B = 256
#define ZP_OFF    10560    // 16 B zero page (bf16 epilogue pad cols)
#define XST_OFF   10576    // 2 rows x 104 chunks x 16 B bf16 (encoder prologue only)
#define T2L_OFF   13904    // T2 ct 0..35: 72 frag-pairs x 2048 B = 147456
#define RED_OFF   13904    // epilogue overlay (T2L dead by then): 16 KiB
#define LDS_BYTES 161360   // ~157.6 KiB of 160 KiB

__global__
__attribute__((amdgpu_flat_work_group_size(1024, 1024), amdgpu_waves_per_eu(4, 4)))
void phasenn_kernel(
    const float* __restrict__ x, const float* __restrict__ W_enc,
    const float* __restrict__ b_enc, const float* __restrict__ xi,
    const float* __restrict__ W_out, const float* __restrict__ b_out,
    float* __restrict__ dout, char* __restrict__ wsb, TCons tc)
{
  __shared__ __align__(16) char smem[LDS_BYTES];

  const int tid  = threadIdx.x;
  const int bk   = blockIdx.x;        // rows bk*2, bk*2+1
  const int w    = tid >> 6;          // 16 waves
  const int lane = tid & 63;
  const int q    = lane >> 4;
  const int b16  = lane & 15;         // MFMA col slot (batch row duplicated x8)
  const int row2 = b16 & 1;           // batch row within block
  const int j4   = b16 >> 2;          // lane's n-subtile j (0..3)
  const int rp   = (b16 >> 1) & 1;    // lane's r-pair (r = rp*2 + {0,1})

  char* T1g = wsb;                    // 256 KiB: (pt 8, F 16) frag-pairs, 2 planes x 1024
  char* T2g = wsb + (256 << 10);      // ct>=36: (ct*2+P2) frag-pairs, 2 planes x 1024

  // ---- LDS init: zero page only
  if (tid < 4) *(unsigned*)(smem + ZP_OFF + tid*4) = 0;

  // ---- xstage: x rows -> bf16 B-frag chunks (chunk ^ row), d>=784 zero (encoder)
  {
    const int row = tid >> 7, dg = tid & 127;
    if (row < 2 && dg < 100) {
      bf16x8 fr = {0,0,0,0,0,0,0,0};
      if (dg < 98) {
        f32x4 v0 = *(const f32x4*)(x + (bk*2 + row)*784 + dg*8);
        f32x4 v1 = *(const f32x4*)(x + (bk*2 + row)*784 + dg*8 + 4);
        #pragma unroll
        for (int i = 0; i < 8; ++i) fr[i] = (short)f2bf(i < 4 ? v0[i] : v1[i-4]);
      }
      *(bf16x8*)(smem + XST_OFF + row*1664 + (((dg ^ row) & 127) << 4)) = fr;
    }
  }

  // ---- table gen: i8 frag-pairs, plane layout (cos @ lane*16, sin @ +1024)
  if (w < 8) {  // T1: wave = ptile. lane: p = w*16+b16, n = F*64 + q*16 + i
    const int p = w*16 + b16;
    for (int F = 0; F < 16; ++F) {
      const int n0 = F*64 + q*16;
      f32x4 v0 = *(const f32x4*)(xi + p*1024 + n0);
      f32x4 v1 = *(const f32x4*)(xi + p*1024 + n0 + 4);
      f32x4 v2 = *(const f32x4*)(xi + p*1024 + n0 + 8);
      f32x4 v3 = *(const f32x4*)(xi + p*1024 + n0 + 12);
      float cv[16], sv[16];
      #pragma unroll
      for (int i = 0; i < 16; ++i) {
        float xv = (i < 4) ? v0[i] : (i < 8) ? v1[i-4] : (i < 12) ? v2[i-8] : v3[i-12];
        sv[i] = __sinf(xv); cv[i] = __cosf(xv);
      }
      i32x4 C = { pk4i8(cv), pk4i8(cv+4), pk4i8(cv+8), pk4i8(cv+12) };
      i32x4 S = { pk4i8(sv), pk4i8(sv+4), pk4i8(sv+8), pk4i8(sv+12) };
      char* dst = T1g + (size_t)(w*16 + F)*2048 + lane*16;
      *(i32x4*)(dst) = C; *(i32x4*)(dst + 1024) = S;
    }
  } else {      // T2: lane: n = ct*16+b16, p = P2*64 + q*16 + i
    const int w2 = w - 8;
    for (int f = 0; f < 16; ++f) {
      const int ct = w2*8 + (f >> 1), P2 = f & 1;
      const int n = ct*16 + b16;
      float cv[16], sv[16];
      #pragma unroll
      for (int i = 0; i < 16; ++i) {
        float xv = xi[(P2*64 + q*16 + i)*1024 + n];
        sv[i] = __sinf(xv); cv[i] = __cosf(xv);
      }
      i32x4 C = { pk4i8(cv), pk4i8(cv+4), pk4i8(cv+8), pk4i8(cv+12) };
      i32x4 S = { pk4i8(sv), pk4i8(sv+4), pk4i8(sv+8), pk4i8(sv+12) };
      char* dst = (ct < 36)
          ? (smem + T2L_OFF + (size_t)(ct*2 + P2)*2048 + lane*16)
          : (T2g + (size_t)(ct*2 + P2)*2048 + lane*16);
      *(i32x4*)(dst) = C; *(i32x4*)(dst + 1024) = S;
    }
  }
  __syncthreads();

  // ---- encoder (bf16 MFMA): unchanged.  Lane keeps 2 phases:
  // n = (w*4+j4)*16 + q*4 + rp*2 + {0,1}, batch row row2.
  float p0[2], ka[2], pwv[2];
  {
    f32x4 pac[4] = {{0,0,0,0},{0,0,0,0},{0,0,0,0},{0,0,0,0}};
    for (int kt = 0; kt < 25; ++kt) {
      const char* baddr =
          smem + XST_OFF + row2*1664 + ((((kt*4 + q) ^ row2) & 127) << 4);
      bf16x8 bfr = *(const bf16x8*)baddr;
      const int d = kt*32 + q*8;
      #pragma unroll
      for (int j = 0; j < 4; ++j) {
        bf16x8 afr = {0,0,0,0,0,0,0,0};
        if (d < 784) {
          const int n = (w*4 + j)*16 + b16;
          f32x4 v0 = *(const f32x4*)(W_enc + n*784 + d);
          f32x4 v1 = *(const f32x4*)(W_enc + n*784 + d + 4);
          #pragma unroll
          for (int i = 0; i < 8; ++i) afr[i] = (short)f2bf(i < 4 ? v0[i] : v1[i-4]);
        }
        pac[j] = __builtin_amdgcn_mfma_f32_16x16x32_bf16(afr, bfr, pac[j], 0, 0, 0);
      }
    }
    f32x4 pc = (j4==0) ? pac[0] : (j4==1) ? pac[1] : (j4==2) ? pac[2] : pac[3];
    float vA = rp ? pc[2] : pc[0];
    float vB = rp ? pc[3] : pc[1];
    const int n0 = (w*4 + j4)*16 + q*4 + rp*2;
    float ph0 = 6.283185307179586f / (1.0f + __expf(-(vA + b_enc[n0])));
    float ph1 = 6.283185307179586f / (1.0f + __expf(-(vB + b_enc[n0 + 1])));
    p0[0] = ph0; pwv[0] = ph0; ka[0] = 0.0f;
    p0[1] = ph1; pwv[1] = ph1; ka[1] = 0.0f;
  }

  const float dtf = 0.03125f, half = 0.015625f;
  const float sixth = (float)(0.03125/6.0);
  const float mscale = (float)(2.0 / (1024.0 * 16129.0));   // BETA/N / 127^2
  const float kscale = (float)(1.0 / 16129.0);              // 1/127^2

  for (int e = 0; e < 64; ++e) {
    float csv[2], snv[2];
    // ---- Phase A: all 64 lanes, 2 phases each; i8 feats, linear layout
    {
      #pragma unroll
      for (int r = 0; r < 2; ++r) {
        snv[r] = __sinf(pwv[r]);
        csv[r] = __cosf(pwv[r]);
      }
      int c0 = __float2int_rn(csv[0]*127.0f) & 255;
      int c1 = __float2int_rn(csv[1]*127.0f) & 255;
      int s0 = __float2int_rn(snv[0]*127.0f) & 255;
      int s1 = __float2int_rn(snv[1]*127.0f) & 255;
      const int n0 = (w*4 + j4)*16 + q*4 + rp*2;
      char* base = smem + A1_OFF + row2*2048 + n0;
      *(unsigned short*)(base)        = (unsigned short)(c0 | (c1 << 8));
      *(unsigned short*)(base + 1024) = (unsigned short)(s0 | (s1 << 8));
    }
    __syncthreads();

    // ---- GEMM1 i8 K=64: m[p][row]; wave = (pt=w&7, kh=w>>3); 16 MFMA/wave
    {
      const int pt = w & 7, kh = w >> 3;
      i32x4 accC = {0,0,0,0}, accS = {0,0,0,0};
      const char* t1b = T1g + (size_t)(pt*16 + kh*8)*2048 + lane*16;
      const char* a1b = smem + A1_OFF + row2*2048;
      #pragma unroll
      for (int i2 = 0; i2 < 8; ++i2) {
        const int F = kh*8 + i2;
        i32x4 ca = *(const i32x4*)(t1b + (size_t)i2*2048);
        i32x4 sa = *(const i32x4*)(t1b + (size_t)i2*2048 + 1024);
        i32x4 bc = *(const i32x4*)(a1b + F*64 + q*16);
        i32x4 bs = *(const i32x4*)(a1b + 1024 + F*64 + q*16);
        accC = __builtin_amdgcn_mfma_i32_16x16x64_i8(ca, bc, accC, 0, 0, 0);
        accS = __builtin_amdgcn_mfma_i32_16x16x64_i8(sa, bs, accS, 0, 0, 0);
      }
      if (b16 < 2) {
        i32x4 acc = accC + accS;
        *(i32x4*)(smem + MBUF_OFF + kh*1056 + b16*528 + ((pt*16 + q*4) << 2)) = acc;
      }
    }
    __syncthreads();

    // ---- softmax (waves 0..1, wave = row): exact i32 m; w i8 (x127), linear
    if (w < 2) {
      const char* mb = smem + MBUF_OFF + w*528 + lane*8;
      int a0 = *(const int*)(mb),        a1 = *(const int*)(mb + 4);
      int b0 = *(const int*)(mb + 1056), b1 = *(const int*)(mb + 1056 + 4);
      float e0 = __expf((float)(a0 + b0) * mscale);
      float e1 = __expf((float)(a1 + b1) * mscale);
      float s = e0 + e1;
      #pragma unroll
      for (int off = 1; off < 64; off <<= 1) s += __shfl_xor(s, off, 64);
      const float inv = 127.0f / s;
      int w0 = __float2int_rn(e0 * inv);
      int w1 = __float2int_rn(e1 * inv);
      *(unsigned short*)(smem + W_OFF + w*128 + lane*2) =
          (unsigned short)((w0 & 255) | (w1 << 8));
    }
    __syncthreads();

    // ---- GEMM2 i8 K=64 + RK4: waves 0..8 read T2 from LDS, 9..15 global.
    // 4 ct x 2 P2 pairs = 16 MFMA/wave; lane selects (j4, rp); cached trig.
    {
      const float swt = tc.s[e], cwt = tc.c[e];
      const int st = e & 3;
      i32x4 wf0 = *(const i32x4*)(smem + W_OFF + row2*128 + q*16);
      i32x4 wf1 = *(const i32x4*)(smem + W_OFF + row2*128 + 64 + q*16);
      i32x4 aC[4] = {{0,0,0,0},{0,0,0,0},{0,0,0,0},{0,0,0,0}};
      i32x4 aS[4] = {{0,0,0,0},{0,0,0,0},{0,0,0,0},{0,0,0,0}};
      if (w < 9) {
        const char* t2b = smem + T2L_OFF + (size_t)(w*8)*2048 + lane*16;
        #pragma unroll
        for (int c = 0; c < 4; ++c)
          #pragma unroll
          for (int P2 = 0; P2 < 2; ++P2) {
            i32x4 ct_ = *(const i32x4*)(t2b + (size_t)(c*2 + P2)*2048);
            i32x4 st_ = *(const i32x4*)(t2b + (size_t)(c*2 + P2)*2048 + 1024);
            i32x4 wf = P2 ? wf1 : wf0;
            aC[c] = __builtin_amdgcn_mfma_i32_16x16x64_i8(ct_, wf, aC[c], 0, 0, 0);
            aS[c] = __builtin_amdgcn_mfma_i32_16x16x64_i8(st_, wf, aS[c], 0, 0, 0);
          }
      } else {
        const char* t2b = T2g + (size_t)(w*8)*2048 + lane*16;
        #pragma unroll
        for (int c = 0; c < 4; ++c)
          #pragma unroll
          for (int P2 = 0; P2 < 2; ++P2) {
            i32x4 ct_ = *(const i32x4*)(t2b + (size_t)(c*2 + P2)*2048);
            i32x4 st_ = *(const i32x4*)(t2b + (size_t)(c*2 + P2)*2048 + 1024);
            i32x4 wf = P2 ? wf1 : wf0;
            aC[c] = __builtin_amdgcn_mfma_i32_16x16x64_i8(ct_, wf, aC[c], 0, 0, 0);
            aS[c] = __builtin_amdgcn_mfma_i32_16x16x64_i8(st_, wf, aS[c], 0, 0, 0);
          }
      }
      i32x4 c4 = (j4==0) ? aC[0] : (j4==1) ? aC[1] : (j4==2) ? aC[2] : aC[3];
      i32x4 s4 = (j4==0) ? aS[0] : (j4==1) ? aS[1] : (j4==2) ? aS[2] : aS[3];
      float vC[2], vS[2];
      vC[0] = (float)(rp ? c4[2] : c4[0]);  vC[1] = (float)(rp ? c4[3] : c4[1]);
      vS[0] = (float)(rp ? s4[2] : s4[0]);  vS[1] = (float)(rp ? s4[3] : s4[1]);
      #pragma unroll
      for (int r = 0; r < 2; ++r) {
        float s_ = snv[r];
        float c_ = csv[r];
        float kv = (s_*vC[r] - c_*vS[r]) * kscale
                 + 0.08f*(swt*c_ - cwt*s_);            // A*sin(wt - phi)
        if (st == 0)      { ka[r]  = kv;           pwv[r] = p0[r] + kv*half; }
        else if (st == 1) { ka[r] += 2.0f*kv;      pwv[r] = p0[r] + kv*half; }
        else if (st == 2) { ka[r] += 2.0f*kv;      pwv[r] = p0[r] + kv*dtf;  }
        else { ka[r] += kv; p0[r] += ka[r]*sixth; pwv[r] = p0[r]; }
      }
    }
  }

  // ---- epilogue (bf16 MFMA): out = [cos phiT, sin phiT] @ W_out^T + b_out
  __syncthreads();
  {  // pack feats bf16 into A1 region (rows 0..1, 4-KB stride); all lanes, 2 each
    u16x2 cp, sp;
    #pragma unroll
    for (int r = 0; r < 2; ++r) {
      float ph = p0[r];
      cp[r] = f2bf(__cosf(ph)); sp[r] = f2bf(__sinf(ph));
    }
    const int cj = (w*4 + j4)*2 + (q >> 1);
    char* base = smem + A1_OFF + row2*4096 + ((q & 1) << 3) + rp*4;
    *(u16x2*)(base + ((cj ^ row2) << 4))        = cp;
    *(u16x2*)(base + ((cj ^ row2) << 4) + 2048) = sp;
  }
  __syncthreads();
  {  // D[cl][row] partial over this wave's 4 ktiles; A = W_out rows (cl<10, pad 0)
    f32x4 acc = {0.f, 0.f, 0.f, 0.f};
    #pragma unroll
    for (int i2 = 0; i2 < 4; ++i2) {
      const int kt = w*4 + i2;
      const int k = kt*32 + q*8;
      bf16x8 afr = {0,0,0,0,0,0,0,0};
      if (b16 < 10) {
        f32x4 v0 = *(const f32x4*)(W_out + b16*2048 + k);
        f32x4 v1 = *(const f32x4*)(W_out + b16*2048 + k + 4);
        #pragma unroll
        for (int i = 0; i < 8; ++i) afr[i] = (short)f2bf(i < 4 ? v0[i] : v1[i-4]);
      }
      const char* baddr = (b16 < 2)
          ? (smem + A1_OFF + b16*4096 + ((((kt*4 + q) ^ b16) & 255) << 4))
          : (smem + ZP_OFF);
      bf16x8 bfr = *(const bf16x8*)baddr;
      acc = __builtin_amdgcn_mfma_f32_16x16x32_bf16(afr, bfr, acc, 0, 0, 0);
    }
    *(f32x4*)(smem + RED_OFF + ((w*64 + lane) << 4)) = acc;
  }
  __syncthreads();
  if (tid < 64) {   // reduce 16 wave-partials; lane: row = tid&15, cl = (tid>>4)*4+r
    f32x4 s = {0.f, 0.f, 0.f, 0.f};
    #pragma unroll
    for (int w2 = 0; w2 < 16; ++w2)
      s += *(const f32x4*)(smem + RED_OFF + ((w2*64 + tid) << 4));
    const int b = tid & 15, q2 = tid >> 4;
    if (b < 2) {
      #pragma unroll
      for (int r = 0; r < 4; ++r) {
        const int cl = q2*4 + r;
        if (cl < 10)
          dout[(bk*2 + b)*10 + cl] = s[r] + b_out[cl];
      }
    }
  }
}

extern "C" void kernel_launch(void* const* d_in, const int* in_sizes, int n_in,
                              void* d_out, int out_size, void* d_ws, size_t ws_size,
                              hipStream_t stream) {
  (void)in_sizes; (void)n_in; (void)ws_size; (void)out_size;
  const float* x     = (const float*)d_in[0];
  const float* W_enc = (const float*)d_in[1];
  const float* b_enc = (const float*)d_in[2];
  const float* xi    = (const float*)d_in[3];
  const float* W_out = (const float*)d_in[4];
  const float* b_out = (const float*)d_in[5];
  float* out = (float*)d_out;
  char* wsb = (char*)d_ws;   // 512 KiB i8 tables; T1 + T2(ct>=36) rewritten per launch

  TCons tc;
  const double OME = 2.0 * 3.14159265358979323846 * 200.0;
  const double dtd = 0.03125;
  const double co[4] = {0.0, 0.5, 0.5, 1.0};
  for (int e = 0; e < 64; ++e) {
    double t = ((double)(e >> 2) + co[e & 3]) * dtd;
    tc.s[e] = (float)sin(OME * t);
    tc.c[e] = (float)cos(OME * t);
  }

  phasenn_kernel<<<dim3(128), dim3(1024), 0, stream>>>(
      x, W_enc, b_enc, xi, W_out, b_out, out, wsb, tc);
}